// Round 1
// baseline (3878.011 us; speedup 1.0000x reference)
//
#include <hip/hip_runtime.h>

#define HW 65536

// ---------------------------------------------------------------------------
// Merge 7x7 + 5x5 + 3x3 kernels into one 7x7, layout [ci][49][32oc]
// ---------------------------------------------------------------------------
__global__ void merge_kernel(const float* __restrict__ k7, const float* __restrict__ k5,
                             const float* __restrict__ k3, float* __restrict__ km, int Cin)
{
    int idx = blockIdx.x * 256 + threadIdx.x;
    int total = Cin * 49 * 32;
    if (idx >= total) return;
    int oc = idx & 31;
    int kk = (idx >> 5) % 49;
    int ci = idx / (49 * 32);
    int ky = kk / 7, kx = kk % 7;
    float v = k7[(oc * Cin + ci) * 49 + kk];
    if (ky >= 1 && ky <= 5 && kx >= 1 && kx <= 5)
        v += k5[(oc * Cin + ci) * 25 + (ky - 1) * 5 + (kx - 1)];
    if (ky >= 2 && ky <= 4 && kx >= 2 && kx <= 4)
        v += k3[(oc * Cin + ci) * 9 + (ky - 2) * 3 + (kx - 2)];
    km[idx] = v;   // idx == (ci*49+kk)*32+oc
}

// ---------------------------------------------------------------------------
// 7x7 SAME conv, 16x16 output tile per block, 16 out-channels per block.
// Optional BN(scale,shift)+ReLU applied to inputs on the fly.
// Also accumulates per-out-channel sum / sumsq for the following BatchNorm.
// Grid: (256 tiles, 2 oc-halves). Block: 256.
// ---------------------------------------------------------------------------
__global__ __launch_bounds__(256) void conv7_kernel(
    const float* __restrict__ inA, int CA,
    const float* __restrict__ sclA, const float* __restrict__ shfA,
    const float* __restrict__ inB,
    const float* __restrict__ sclB, const float* __restrict__ shfB,
    const float* __restrict__ km, int Cin,
    float* __restrict__ out, float* __restrict__ ssum, float* __restrict__ ssq)
{
    __shared__ float tile[4 * 22 * 22];
    int t  = threadIdx.x;
    int tx = t & 15, ty = t >> 4;
    int bx = blockIdx.x & 15, by = blockIdx.x >> 4;
    int px0 = bx * 16, py0 = by * 16;
    int ocb = blockIdx.y * 16;

    float acc[16];
#pragma unroll
    for (int i = 0; i < 16; ++i) acc[i] = 0.f;

    for (int cc = 0; cc < Cin; cc += 4) {
        __syncthreads();
        for (int i = t; i < 4 * 484; i += 256) {
            int ci = i / 484, r = i % 484;
            int ly = r / 22, lx = r % 22;
            int c = cc + ci;
            int gy = py0 + ly - 3, gx = px0 + lx - 3;
            float v = 0.f;
            if (c < Cin && gy >= 0 && gy < 256 && gx >= 0 && gx < 256) {
                if (c < CA) {
                    v = inA[c * HW + gy * 256 + gx];
                    if (sclA) v = fmaxf(v * sclA[c] + shfA[c], 0.f);
                } else {
                    int c2 = c - CA;
                    v = inB[c2 * HW + gy * 256 + gx];
                    v = fmaxf(v * sclB[c2] + shfB[c2], 0.f);
                }
            }
            tile[i] = v;
        }
        __syncthreads();
        int cmax = Cin - cc; if (cmax > 4) cmax = 4;
        for (int ci = 0; ci < cmax; ++ci) {
            const float* wbase = km + (cc + ci) * 49 * 32 + ocb;
            const float* trow = tile + ci * 484;
#pragma unroll
            for (int ky = 0; ky < 7; ++ky) {
#pragma unroll
                for (int kx = 0; kx < 7; ++kx) {
                    float xv = trow[(ty + ky) * 22 + tx + kx];
                    const float* wk = wbase + (ky * 7 + kx) * 32;   // uniform -> s_load
#pragma unroll
                    for (int oc = 0; oc < 16; ++oc)
                        acc[oc] = fmaf(xv, wk[oc], acc[oc]);
                }
            }
        }
    }

    int n = (py0 + ty) * 256 + px0 + tx;
#pragma unroll
    for (int oc = 0; oc < 16; ++oc)
        out[(ocb + oc) * HW + n] = acc[oc];

    // per-wave reduction of sum / sumsq, then one atomic per wave per channel
#pragma unroll
    for (int oc = 0; oc < 16; ++oc) {
        float s = acc[oc];
        float q = s * s;
#pragma unroll
        for (int d = 32; d >= 1; d >>= 1) {
            s += __shfl_down(s, d);
            q += __shfl_down(q, d);
        }
        if ((t & 63) == 0) {
            atomicAdd(&ssum[ocb + oc], s);
            atomicAdd(&ssq[ocb + oc], q);
        }
    }
}

// ---------------------------------------------------------------------------
// BN params: scale = g * rsqrt(var+1e-5), shift = beta - mu*scale
// ---------------------------------------------------------------------------
__global__ void bnp_kernel(const float* __restrict__ ssum, const float* __restrict__ ssq,
                           const float* __restrict__ g, const float* __restrict__ beta,
                           float* __restrict__ scl, float* __restrict__ shf)
{
    int c = threadIdx.x;
    float mu  = ssum[c] * (1.f / 65536.f);
    float var = ssq[c] * (1.f / 65536.f) - mu * mu;
    float s = g[c] * rsqrtf(var + 1e-5f);
    scl[c] = s;
    shf[c] = beta[c] - mu * s;
}

// ---------------------------------------------------------------------------
// 1x1 conv (96 -> 15) + ReLU, writes pf[0..14]; copies x into pf[15..117]
// ---------------------------------------------------------------------------
__global__ __launch_bounds__(256) void feat_kernel(
    const float* __restrict__ y1, const float* __restrict__ y2, const float* __restrict__ y3,
    const float* __restrict__ bn,  // [scl1|shf1|scl2|shf2|scl3|shf3] x32
    const float* __restrict__ w, const float* __restrict__ b,
    const float* __restrict__ x, float* __restrict__ pf)
{
    int n = blockIdx.x * 256 + threadIdx.x;
    float facc[15];
#pragma unroll
    for (int oc = 0; oc < 15; ++oc) facc[oc] = b[oc];

    const float* srcs[3] = {y1, y2, y3};
#pragma unroll
    for (int s = 0; s < 3; ++s) {
        const float* src = srcs[s];
        const float* scl = bn + s * 64;
        const float* shf = scl + 32;
        for (int c = 0; c < 32; ++c) {
            float v = fmaxf(src[c * HW + n] * scl[c] + shf[c], 0.f);
#pragma unroll
            for (int oc = 0; oc < 15; ++oc)
                facc[oc] = fmaf(v, w[oc * 96 + s * 32 + c], facc[oc]);
        }
    }
#pragma unroll
    for (int oc = 0; oc < 15; ++oc)
        pf[oc * HW + n] = fmaxf(facc[oc], 0.f);
    for (int c = 0; c < 103; ++c)
        pf[(15 + c) * HW + n] = x[c * HW + n];
}

// ---------------------------------------------------------------------------
// c0: block-average pf over 16x16 blocks -> cent[c][s]
// ---------------------------------------------------------------------------
__global__ void c0_kernel(const float* __restrict__ pf, float* __restrict__ cent)
{
    int c = blockIdx.x;        // 118
    int s = threadIdx.x;       // 256
    int sy = s >> 4, sx = s & 15;
    const float* base = pf + c * HW + (sy * 16) * 256 + sx * 16;
    float acc = 0.f;
    for (int dy = 0; dy < 16; ++dy)
#pragma unroll
        for (int dx = 0; dx < 16; ++dx)
            acc += base[dy * 256 + dx];
    cent[c * 256 + s] = acc * (1.f / 256.f);
}

__global__ void cn2_kernel(const float* __restrict__ cent, float* __restrict__ cn2)
{
    int s = threadIdx.x;
    float a = 0.f;
    for (int c = 0; c < 118; ++c) { float v = cent[c * 256 + s]; a = fmaf(v, v, a); }
    cn2[s] = a;
}

// ---------------------------------------------------------------------------
// dist + softmax: Q[s,n] = softmax_s( 2*dot[s,n] - cn2[s] )
// Block: 256 threads handle all 256 s for 64 pixels. Grid: 1024.
// ---------------------------------------------------------------------------
__global__ __launch_bounds__(256) void dist_kernel(
    const float* __restrict__ cent, const float* __restrict__ cn2,
    const float* __restrict__ pf, float* __restrict__ Q)
{
    __shared__ __align__(16) float lc[2048];   // 8 c  x 256 s
    __shared__ __align__(16) float lp[512];    // 8 c  x 64 n
    __shared__ float red[64 * 17];             // [n][s_grp] padded

    int t = threadIdx.x;
    int n0 = blockIdx.x * 64;
    int sg = t >> 4, ng = t & 15;

    float acc[16][4];
#pragma unroll
    for (int i = 0; i < 16; ++i)
#pragma unroll
        for (int j = 0; j < 4; ++j) acc[i][j] = 0.f;

    for (int cc = 0; cc < 118; cc += 8) {
#pragma unroll
        for (int k = 0; k < 8; ++k) {
            int i = t + k * 256;
            int ci = i >> 8, s = i & 255;
            lc[i] = (cc + ci < 118) ? cent[(cc + ci) * 256 + s] : 0.f;
        }
#pragma unroll
        for (int k = 0; k < 2; ++k) {
            int i = t + k * 256;
            int ci = i >> 6, j = i & 63;
            lp[i] = (cc + ci < 118) ? pf[(cc + ci) * HW + n0 + j] : 0.f;
        }
        __syncthreads();
#pragma unroll
        for (int ci = 0; ci < 8; ++ci) {
            float p[4];
            *(float4*)p = *(const float4*)&lp[ci * 64 + ng * 4];
#pragma unroll
            for (int k = 0; k < 4; ++k) {
                float cv[4];
                *(float4*)cv = *(const float4*)&lc[ci * 256 + sg * 16 + k * 4];
#pragma unroll
                for (int e = 0; e < 4; ++e)
#pragma unroll
                    for (int ni = 0; ni < 4; ++ni)
                        acc[k * 4 + e][ni] = fmaf(cv[e], p[ni], acc[k * 4 + e][ni]);
            }
        }
        __syncthreads();
    }

    // a = 2*dot - cn2[s]
#pragma unroll
    for (int si = 0; si < 16; ++si) {
        float c2 = cn2[sg * 16 + si];
#pragma unroll
        for (int ni = 0; ni < 4; ++ni)
            acc[si][ni] = 2.f * acc[si][ni] - c2;
    }
    // softmax over s (cross-thread via red)
    float m[4];
#pragma unroll
    for (int ni = 0; ni < 4; ++ni) {
        float mm = acc[0][ni];
#pragma unroll
        for (int si = 1; si < 16; ++si) mm = fmaxf(mm, acc[si][ni]);
        red[(ng * 4 + ni) * 17 + sg] = mm;
    }
    __syncthreads();
#pragma unroll
    for (int ni = 0; ni < 4; ++ni) {
        float mm = red[(ng * 4 + ni) * 17];
#pragma unroll
        for (int k = 1; k < 16; ++k) mm = fmaxf(mm, red[(ng * 4 + ni) * 17 + k]);
        m[ni] = mm;
    }
    __syncthreads();
    float sm[4] = {0.f, 0.f, 0.f, 0.f};
#pragma unroll
    for (int si = 0; si < 16; ++si)
#pragma unroll
        for (int ni = 0; ni < 4; ++ni) {
            float e = __expf(acc[si][ni] - m[ni]);
            acc[si][ni] = e;
            sm[ni] += e;
        }
#pragma unroll
    for (int ni = 0; ni < 4; ++ni) red[(ng * 4 + ni) * 17 + sg] = sm[ni];
    __syncthreads();
#pragma unroll
    for (int ni = 0; ni < 4; ++ni) {
        float s = 0.f;
#pragma unroll
        for (int k = 0; k < 16; ++k) s += red[(ng * 4 + ni) * 17 + k];
        m[ni] = 1.f / s;
    }
#pragma unroll
    for (int si = 0; si < 16; ++si) {
        float4 o;
        o.x = acc[si][0] * m[0];
        o.y = acc[si][1] * m[1];
        o.z = acc[si][2] * m[2];
        o.w = acc[si][3] * m[3];
        *(float4*)&Q[(sg * 16 + si) * HW + n0 + ng * 4] = o;
    }
}

// ---------------------------------------------------------------------------
// cn numerator: cn_raw[c][s] += sum_n Q[s,n]*pix[c,n]; row 118 = ones channel
// Grid: (64 K-slices, 4 s-blocks). Block: 256 (8 s_sub x 32 c_sub).
// ---------------------------------------------------------------------------
__global__ __launch_bounds__(256) void cn_kernel(
    const float* __restrict__ Q, const float* __restrict__ pf,
    float* __restrict__ cn_raw)
{
    __shared__ __align__(16) float Qt[64 * 16];    // [s][j]
    __shared__ __align__(16) float Pt[16 * 128];   // [j][c] padded to 128
    int t = threadIdx.x;
    int ssub = t >> 5;      // 0..7
    int csub = t & 31;      // 0..31
    int sb = blockIdx.y * 64;
    int n0 = blockIdx.x * 1024;

    float acc[8][4];
#pragma unroll
    for (int i = 0; i < 8; ++i)
#pragma unroll
        for (int j = 0; j < 4; ++j) acc[i][j] = 0.f;

    for (int nc = 0; nc < 1024; nc += 16) {
#pragma unroll
        for (int k = 0; k < 4; ++k) {
            int i = t + k * 256;
            int s = i >> 4, j = i & 15;
            Qt[i] = Q[(sb + s) * HW + n0 + nc + j];
        }
#pragma unroll
        for (int k = 0; k < 8; ++k) {
            int i = t + k * 256;
            int c = i >> 4, j = i & 15;
            float v;
            if (c < 118) v = pf[c * HW + n0 + nc + j];
            else v = (c == 118) ? 1.f : 0.f;
            Pt[j * 128 + c] = v;
        }
        __syncthreads();
#pragma unroll
        for (int j4 = 0; j4 < 16; j4 += 4) {
            float p[4][4];
#pragma unroll
            for (int jj = 0; jj < 4; ++jj)
                *(float4*)p[jj] = *(const float4*)&Pt[(j4 + jj) * 128 + csub * 4];
#pragma unroll
            for (int si = 0; si < 8; ++si) {
                float q[4];
                *(float4*)q = *(const float4*)&Qt[(ssub * 8 + si) * 16 + j4];
#pragma unroll
                for (int jj = 0; jj < 4; ++jj)
#pragma unroll
                    for (int ci = 0; ci < 4; ++ci)
                        acc[si][ci] = fmaf(q[jj], p[jj][ci], acc[si][ci]);
            }
        }
        __syncthreads();
    }
#pragma unroll
    for (int si = 0; si < 8; ++si)
#pragma unroll
        for (int ci = 0; ci < 4; ++ci) {
            int c = csub * 4 + ci;
            if (c < 119)
                atomicAdd(&cn_raw[c * 256 + sb + ssub * 8 + si], acc[si][ci]);
        }
}

// ---------------------------------------------------------------------------
// centroid update: cent = cn_raw / (qsum + eps); cn2 = sum_c cent^2
// ---------------------------------------------------------------------------
__global__ void upd_kernel(const float* __restrict__ cn_raw, float* __restrict__ cent,
                           float* __restrict__ cn2)
{
    int s = threadIdx.x;
    float inv = 1.f / (cn_raw[118 * 256 + s] + 1e-8f);
    float a = 0.f;
    for (int c = 0; c < 118; ++c) {
        float v = cn_raw[c * 256 + s] * inv;
        cent[c * 256 + s] = v;
        a = fmaf(v, v, a);
    }
    cn2[s] = a;
}

// ---------------------------------------------------------------------------
extern "C" void kernel_launch(void* const* d_in, const int* in_sizes, int n_in,
                              void* d_out, int out_size, void* d_ws, size_t ws_size,
                              hipStream_t stream)
{
    const float* x     = (const float*)d_in[0];
    const float* s1k7  = (const float*)d_in[1];
    const float* s1k5  = (const float*)d_in[2];
    const float* s1k3  = (const float*)d_in[3];
    const float* s1g   = (const float*)d_in[5];
    const float* s1be  = (const float*)d_in[6];
    const float* s2k7  = (const float*)d_in[7];
    const float* s2k5  = (const float*)d_in[8];
    const float* s2k3  = (const float*)d_in[9];
    const float* s2g   = (const float*)d_in[11];
    const float* s2be  = (const float*)d_in[12];
    const float* s3k7  = (const float*)d_in[13];
    const float* s3k5  = (const float*)d_in[14];
    const float* s3k3  = (const float*)d_in[15];
    const float* s3g   = (const float*)d_in[17];
    const float* s3be  = (const float*)d_in[18];
    const float* outw  = (const float*)d_in[19];
    const float* outb  = (const float*)d_in[20];

    float* ws = (float*)d_ws;
    size_t off = 0;
    float* km1  = ws + off; off += 103 * 49 * 32;
    float* km2  = ws + off; off += 32 * 49 * 32;
    float* km3  = ws + off; off += 64 * 49 * 32;
    float* y1   = ws + off; off += 32 * HW;
    float* y2   = ws + off; off += 32 * HW;
    float* y3   = ws + off; off += 32 * HW;
    float* stats= ws + off; off += 192;   // sum1,sq1,sum2,sq2,sum3,sq3
    float* bn   = ws + off; off += 192;   // scl1,shf1,scl2,shf2,scl3,shf3
    float* pf   = ws + off; off += 118 * HW;
    float* cent = ws + off; off += 118 * 256;
    float* cnr  = ws + off; off += 119 * 256;
    float* cn2  = ws + off; off += 256;

    hipMemsetAsync(stats, 0, 192 * sizeof(float), stream);
    merge_kernel<<<(103 * 49 * 32 + 255) / 256, 256, 0, stream>>>(s1k7, s1k5, s1k3, km1, 103);
    merge_kernel<<<(32 * 49 * 32 + 255) / 256, 256, 0, stream>>>(s2k7, s2k5, s2k3, km2, 32);
    merge_kernel<<<(64 * 49 * 32 + 255) / 256, 256, 0, stream>>>(s3k7, s3k5, s3k3, km3, 64);

    conv7_kernel<<<dim3(256, 2), 256, 0, stream>>>(x, 103, nullptr, nullptr,
                                                   nullptr, nullptr, nullptr,
                                                   km1, 103, y1, stats + 0, stats + 32);
    bnp_kernel<<<1, 32, 0, stream>>>(stats + 0, stats + 32, s1g, s1be, bn + 0, bn + 32);

    conv7_kernel<<<dim3(256, 2), 256, 0, stream>>>(y1, 32, bn + 0, bn + 32,
                                                   nullptr, nullptr, nullptr,
                                                   km2, 32, y2, stats + 64, stats + 96);
    bnp_kernel<<<1, 32, 0, stream>>>(stats + 64, stats + 96, s2g, s2be, bn + 64, bn + 96);

    conv7_kernel<<<dim3(256, 2), 256, 0, stream>>>(y1, 32, bn + 0, bn + 32,
                                                   y2, bn + 64, bn + 96,
                                                   km3, 64, y3, stats + 128, stats + 160);
    bnp_kernel<<<1, 32, 0, stream>>>(stats + 128, stats + 160, s3g, s3be, bn + 128, bn + 160);

    feat_kernel<<<256, 256, 0, stream>>>(y1, y2, y3, bn, outw, outb, x, pf);
    c0_kernel<<<118, 256, 0, stream>>>(pf, cent);
    cn2_kernel<<<1, 256, 0, stream>>>(cent, cn2);

    float* Q = (float*)d_out;
    for (int it = 0; it < 5; ++it) {
        dist_kernel<<<1024, 256, 0, stream>>>(cent, cn2, pf, Q);
        hipMemsetAsync(cnr, 0, 119 * 256 * sizeof(float), stream);
        cn_kernel<<<dim3(64, 4), 256, 0, stream>>>(Q, pf, cnr);
        upd_kernel<<<1, 256, 0, stream>>>(cnr, cent, cn2);
    }
    dist_kernel<<<1024, 256, 0, stream>>>(cent, cn2, pf, Q);
}

// Round 2
// 2466.171 us; speedup vs baseline: 1.5725x; 1.5725x over previous
//
#include <hip/hip_runtime.h>

#define HW 65536

// ---------------------------------------------------------------------------
// Merge 7x7 + 5x5 + 3x3 kernels into one 7x7, layout [ci][49][32oc]
// ---------------------------------------------------------------------------
__global__ void merge_kernel(const float* __restrict__ k7, const float* __restrict__ k5,
                             const float* __restrict__ k3, float* __restrict__ km, int Cin)
{
    int idx = blockIdx.x * 256 + threadIdx.x;
    int total = Cin * 49 * 32;
    if (idx >= total) return;
    int oc = idx & 31;
    int kk = (idx >> 5) % 49;
    int ci = idx / (49 * 32);
    int ky = kk / 7, kx = kk % 7;
    float v = k7[(oc * Cin + ci) * 49 + kk];
    if (ky >= 1 && ky <= 5 && kx >= 1 && kx <= 5)
        v += k5[(oc * Cin + ci) * 25 + (ky - 1) * 5 + (kx - 1)];
    if (ky >= 2 && ky <= 4 && kx >= 2 && kx <= 4)
        v += k3[(oc * Cin + ci) * 9 + (ky - 2) * 3 + (kx - 2)];
    km[idx] = v;   // idx == (ci*49+kk)*32+oc
}

// ---------------------------------------------------------------------------
// 7x7 SAME conv, 16x16 output tile per block, 16 out-channels per block,
// input channels split 3 ways across blockIdx.z -> partial planes.
// Grid: (256 tiles, 2 oc-halves, 3 cin-splits). Block: 256.
// LDS tile row stride padded to 24 -> exact 2-way bank aliasing (free).
// ---------------------------------------------------------------------------
__global__ __launch_bounds__(256) void conv7_kernel(
    const float* __restrict__ inA, int CA,
    const float* __restrict__ sclA, const float* __restrict__ shfA,
    const float* __restrict__ inB,
    const float* __restrict__ sclB, const float* __restrict__ shfB,
    const float* __restrict__ km, int Cin,
    float* __restrict__ part)
{
    __shared__ float tile[4 * 528];   // 4 ci x 22 rows x 24 (padded)
    int t  = threadIdx.x;
    int tx = t & 15, ty = t >> 4;
    int bx = blockIdx.x & 15, by = blockIdx.x >> 4;
    int px0 = bx * 16, py0 = by * 16;
    int ocb = blockIdx.y * 16;
    int split = (Cin + 2) / 3;
    int cin0 = blockIdx.z * split;
    int cin1 = cin0 + split; if (cin1 > Cin) cin1 = Cin;

    float acc[16];
#pragma unroll
    for (int i = 0; i < 16; ++i) acc[i] = 0.f;

    for (int cc = cin0; cc < cin1; cc += 4) {
        __syncthreads();
        for (int i = t; i < 4 * 484; i += 256) {
            int ci = i / 484, r = i % 484;
            int ly = r / 22, lx = r % 22;
            int c = cc + ci;
            int gy = py0 + ly - 3, gx = px0 + lx - 3;
            float v = 0.f;
            if (c < cin1 && gy >= 0 && gy < 256 && gx >= 0 && gx < 256) {
                if (c < CA) {
                    v = inA[c * HW + gy * 256 + gx];
                    if (sclA) v = fmaxf(v * sclA[c] + shfA[c], 0.f);
                } else {
                    int c2 = c - CA;
                    v = inB[c2 * HW + gy * 256 + gx];
                    v = fmaxf(v * sclB[c2] + shfB[c2], 0.f);
                }
            }
            tile[ci * 528 + ly * 24 + lx] = v;
        }
        __syncthreads();
        int cmax = cin1 - cc; if (cmax > 4) cmax = 4;
        for (int ci = 0; ci < cmax; ++ci) {
            const float* wbase = km + (cc + ci) * 49 * 32 + ocb;
            const float* trow = tile + ci * 528;
#pragma unroll
            for (int ky = 0; ky < 7; ++ky) {
#pragma unroll
                for (int kx = 0; kx < 7; ++kx) {
                    float xv = trow[(ty + ky) * 24 + tx + kx];
                    const float* wk = wbase + (ky * 7 + kx) * 32;   // uniform -> s_load
#pragma unroll
                    for (int oc = 0; oc < 16; ++oc)
                        acc[oc] = fmaf(xv, wk[oc], acc[oc]);
                }
            }
        }
    }

    int n = (py0 + ty) * 256 + px0 + tx;
    float* o = part + (size_t)blockIdx.z * 32 * HW;
#pragma unroll
    for (int oc = 0; oc < 16; ++oc)
        o[(ocb + oc) * HW + n] = acc[oc];
}

// ---------------------------------------------------------------------------
// Sum 3 partial planes -> y, and accumulate per-channel sum/sumsq for BN.
// Grid: 1024 blocks (32 channels x 32 segments). Block: 256 (8 floats each).
// ---------------------------------------------------------------------------
__global__ __launch_bounds__(256) void reduce3_kernel(
    const float* __restrict__ part, float* __restrict__ y,
    float* __restrict__ ssum, float* __restrict__ ssq)
{
    int b = blockIdx.x;
    int c = b >> 5, seg = b & 31;
    int base = c * HW + seg * 2048 + threadIdx.x * 8;

    float s = 0.f, q = 0.f;
#pragma unroll
    for (int h = 0; h < 2; ++h) {
        int o = base + h * 4;
        float4 a0 = *(const float4*)&part[o];
        float4 a1 = *(const float4*)&part[32 * HW + o];
        float4 a2 = *(const float4*)&part[64 * HW + o];
        float4 v;
        v.x = a0.x + a1.x + a2.x;
        v.y = a0.y + a1.y + a2.y;
        v.z = a0.z + a1.z + a2.z;
        v.w = a0.w + a1.w + a2.w;
        *(float4*)&y[o] = v;
        s += v.x + v.y + v.z + v.w;
        q = fmaf(v.x, v.x, q); q = fmaf(v.y, v.y, q);
        q = fmaf(v.z, v.z, q); q = fmaf(v.w, v.w, q);
    }
#pragma unroll
    for (int d = 32; d >= 1; d >>= 1) {
        s += __shfl_down(s, d);
        q += __shfl_down(q, d);
    }
    __shared__ float ls[4], lq[4];
    int w = threadIdx.x >> 6;
    if ((threadIdx.x & 63) == 0) { ls[w] = s; lq[w] = q; }
    __syncthreads();
    if (threadIdx.x == 0) {
        float S = ls[0] + ls[1] + ls[2] + ls[3];
        float Q = lq[0] + lq[1] + lq[2] + lq[3];
        atomicAdd(&ssum[c], S);
        atomicAdd(&ssq[c], Q);
    }
}

// ---------------------------------------------------------------------------
// BN params: scale = g * rsqrt(var+1e-5), shift = beta - mu*scale
// ---------------------------------------------------------------------------
__global__ void bnp_kernel(const float* __restrict__ ssum, const float* __restrict__ ssq,
                           const float* __restrict__ g, const float* __restrict__ beta,
                           float* __restrict__ scl, float* __restrict__ shf)
{
    int c = threadIdx.x;
    float mu  = ssum[c] * (1.f / 65536.f);
    float var = ssq[c] * (1.f / 65536.f) - mu * mu;
    float s = g[c] * rsqrtf(var + 1e-5f);
    scl[c] = s;
    shf[c] = beta[c] - mu * s;
}

// ---------------------------------------------------------------------------
// 1x1 conv (96 -> 15) + ReLU, writes pf[0..14]; copies x into pf[15..117]
// ---------------------------------------------------------------------------
__global__ __launch_bounds__(256) void feat_kernel(
    const float* __restrict__ y1, const float* __restrict__ y2, const float* __restrict__ y3,
    const float* __restrict__ bn,  // [scl1|shf1|scl2|shf2|scl3|shf3] x32
    const float* __restrict__ w, const float* __restrict__ b,
    const float* __restrict__ x, float* __restrict__ pf)
{
    int n = blockIdx.x * 256 + threadIdx.x;
    float facc[15];
#pragma unroll
    for (int oc = 0; oc < 15; ++oc) facc[oc] = b[oc];

    const float* srcs[3] = {y1, y2, y3};
#pragma unroll
    for (int s = 0; s < 3; ++s) {
        const float* src = srcs[s];
        const float* scl = bn + s * 64;
        const float* shf = scl + 32;
        for (int c = 0; c < 32; ++c) {
            float v = fmaxf(src[c * HW + n] * scl[c] + shf[c], 0.f);
#pragma unroll
            for (int oc = 0; oc < 15; ++oc)
                facc[oc] = fmaf(v, w[oc * 96 + s * 32 + c], facc[oc]);
        }
    }
#pragma unroll
    for (int oc = 0; oc < 15; ++oc)
        pf[oc * HW + n] = fmaxf(facc[oc], 0.f);
    for (int c = 0; c < 103; ++c)
        pf[(15 + c) * HW + n] = x[c * HW + n];
}

// ---------------------------------------------------------------------------
// c0: block-average pf over 16x16 blocks -> cent[c][s]
// ---------------------------------------------------------------------------
__global__ void c0_kernel(const float* __restrict__ pf, float* __restrict__ cent)
{
    int c = blockIdx.x;        // 118
    int s = threadIdx.x;       // 256
    int sy = s >> 4, sx = s & 15;
    const float* base = pf + c * HW + (sy * 16) * 256 + sx * 16;
    float acc = 0.f;
    for (int dy = 0; dy < 16; ++dy)
#pragma unroll
        for (int dx = 0; dx < 16; ++dx)
            acc += base[dy * 256 + dx];
    cent[c * 256 + s] = acc * (1.f / 256.f);
}

__global__ void cn2_kernel(const float* __restrict__ cent, float* __restrict__ cn2)
{
    int s = threadIdx.x;
    float a = 0.f;
    for (int c = 0; c < 118; ++c) { float v = cent[c * 256 + s]; a = fmaf(v, v, a); }
    cn2[s] = a;
}

// ---------------------------------------------------------------------------
// dist + softmax: Q[s,n] = softmax_s( 2*dot[s,n] - cn2[s] )
// Block: 256 threads handle all 256 s for 64 pixels. Grid: 1024.
// ---------------------------------------------------------------------------
__global__ __launch_bounds__(256) void dist_kernel(
    const float* __restrict__ cent, const float* __restrict__ cn2,
    const float* __restrict__ pf, float* __restrict__ Q)
{
    __shared__ __align__(16) float lc[2048];   // 8 c  x 256 s
    __shared__ __align__(16) float lp[512];    // 8 c  x 64 n
    __shared__ float red[64 * 17];             // [n][s_grp] padded

    int t = threadIdx.x;
    int n0 = blockIdx.x * 64;
    int sg = t >> 4, ng = t & 15;

    float acc[16][4];
#pragma unroll
    for (int i = 0; i < 16; ++i)
#pragma unroll
        for (int j = 0; j < 4; ++j) acc[i][j] = 0.f;

    for (int cc = 0; cc < 118; cc += 8) {
#pragma unroll
        for (int k = 0; k < 8; ++k) {
            int i = t + k * 256;
            int ci = i >> 8, s = i & 255;
            lc[i] = (cc + ci < 118) ? cent[(cc + ci) * 256 + s] : 0.f;
        }
#pragma unroll
        for (int k = 0; k < 2; ++k) {
            int i = t + k * 256;
            int ci = i >> 6, j = i & 63;
            lp[i] = (cc + ci < 118) ? pf[(cc + ci) * HW + n0 + j] : 0.f;
        }
        __syncthreads();
#pragma unroll
        for (int ci = 0; ci < 8; ++ci) {
            float p[4];
            *(float4*)p = *(const float4*)&lp[ci * 64 + ng * 4];
#pragma unroll
            for (int k = 0; k < 4; ++k) {
                float cv[4];
                *(float4*)cv = *(const float4*)&lc[ci * 256 + sg * 16 + k * 4];
#pragma unroll
                for (int e = 0; e < 4; ++e)
#pragma unroll
                    for (int ni = 0; ni < 4; ++ni)
                        acc[k * 4 + e][ni] = fmaf(cv[e], p[ni], acc[k * 4 + e][ni]);
            }
        }
        __syncthreads();
    }

    // a = 2*dot - cn2[s]
#pragma unroll
    for (int si = 0; si < 16; ++si) {
        float c2 = cn2[sg * 16 + si];
#pragma unroll
        for (int ni = 0; ni < 4; ++ni)
            acc[si][ni] = 2.f * acc[si][ni] - c2;
    }
    // softmax over s (cross-thread via red)
    float m[4];
#pragma unroll
    for (int ni = 0; ni < 4; ++ni) {
        float mm = acc[0][ni];
#pragma unroll
        for (int si = 1; si < 16; ++si) mm = fmaxf(mm, acc[si][ni]);
        red[(ng * 4 + ni) * 17 + sg] = mm;
    }
    __syncthreads();
#pragma unroll
    for (int ni = 0; ni < 4; ++ni) {
        float mm = red[(ng * 4 + ni) * 17];
#pragma unroll
        for (int k = 1; k < 16; ++k) mm = fmaxf(mm, red[(ng * 4 + ni) * 17 + k]);
        m[ni] = mm;
    }
    __syncthreads();
    float sm[4] = {0.f, 0.f, 0.f, 0.f};
#pragma unroll
    for (int si = 0; si < 16; ++si)
#pragma unroll
        for (int ni = 0; ni < 4; ++ni) {
            float e = __expf(acc[si][ni] - m[ni]);
            acc[si][ni] = e;
            sm[ni] += e;
        }
#pragma unroll
    for (int ni = 0; ni < 4; ++ni) red[(ng * 4 + ni) * 17 + sg] = sm[ni];
    __syncthreads();
#pragma unroll
    for (int ni = 0; ni < 4; ++ni) {
        float s = 0.f;
#pragma unroll
        for (int k = 0; k < 16; ++k) s += red[(ng * 4 + ni) * 17 + k];
        m[ni] = 1.f / s;
    }
#pragma unroll
    for (int si = 0; si < 16; ++si) {
        float4 o;
        o.x = acc[si][0] * m[0];
        o.y = acc[si][1] * m[1];
        o.z = acc[si][2] * m[2];
        o.w = acc[si][3] * m[3];
        *(float4*)&Q[(sg * 16 + si) * HW + n0 + ng * 4] = o;
    }
}

// ---------------------------------------------------------------------------
// cn numerator: cn_raw[c][s] += sum_n Q[s,n]*pix[c,n]; row 118 = ones channel
// Grid: (64 K-slices, 4 s-blocks). Block: 256 (8 s_sub x 32 c_sub).
// ---------------------------------------------------------------------------
__global__ __launch_bounds__(256) void cn_kernel(
    const float* __restrict__ Q, const float* __restrict__ pf,
    float* __restrict__ cn_raw)
{
    __shared__ __align__(16) float Qt[64 * 16];    // [s][j]
    __shared__ __align__(16) float Pt[16 * 128];   // [j][c] padded to 128
    int t = threadIdx.x;
    int ssub = t >> 5;      // 0..7
    int csub = t & 31;      // 0..31
    int sb = blockIdx.y * 64;
    int n0 = blockIdx.x * 1024;

    float acc[8][4];
#pragma unroll
    for (int i = 0; i < 8; ++i)
#pragma unroll
        for (int j = 0; j < 4; ++j) acc[i][j] = 0.f;

    for (int nc = 0; nc < 1024; nc += 16) {
#pragma unroll
        for (int k = 0; k < 4; ++k) {
            int i = t + k * 256;
            int s = i >> 4, j = i & 15;
            Qt[i] = Q[(sb + s) * HW + n0 + nc + j];
        }
#pragma unroll
        for (int k = 0; k < 8; ++k) {
            int i = t + k * 256;
            int c = i >> 4, j = i & 15;
            float v;
            if (c < 118) v = pf[c * HW + n0 + nc + j];
            else v = (c == 118) ? 1.f : 0.f;
            Pt[j * 128 + c] = v;
        }
        __syncthreads();
#pragma unroll
        for (int j4 = 0; j4 < 16; j4 += 4) {
            float p[4][4];
#pragma unroll
            for (int jj = 0; jj < 4; ++jj)
                *(float4*)p[jj] = *(const float4*)&Pt[(j4 + jj) * 128 + csub * 4];
#pragma unroll
            for (int si = 0; si < 8; ++si) {
                float q[4];
                *(float4*)q = *(const float4*)&Qt[(ssub * 8 + si) * 16 + j4];
#pragma unroll
                for (int jj = 0; jj < 4; ++jj)
#pragma unroll
                    for (int ci = 0; ci < 4; ++ci)
                        acc[si][ci] = fmaf(q[jj], p[jj][ci], acc[si][ci]);
            }
        }
        __syncthreads();
    }
#pragma unroll
    for (int si = 0; si < 8; ++si)
#pragma unroll
        for (int ci = 0; ci < 4; ++ci) {
            int c = csub * 4 + ci;
            if (c < 119)
                atomicAdd(&cn_raw[c * 256 + sb + ssub * 8 + si], acc[si][ci]);
        }
}

// ---------------------------------------------------------------------------
// centroid update: cent = cn_raw / (qsum + eps); cn2 = sum_c cent^2
// ---------------------------------------------------------------------------
__global__ void upd_kernel(const float* __restrict__ cn_raw, float* __restrict__ cent,
                           float* __restrict__ cn2)
{
    int s = threadIdx.x;
    float inv = 1.f / (cn_raw[118 * 256 + s] + 1e-8f);
    float a = 0.f;
    for (int c = 0; c < 118; ++c) {
        float v = cn_raw[c * 256 + s] * inv;
        cent[c * 256 + s] = v;
        a = fmaf(v, v, a);
    }
    cn2[s] = a;
}

// ---------------------------------------------------------------------------
extern "C" void kernel_launch(void* const* d_in, const int* in_sizes, int n_in,
                              void* d_out, int out_size, void* d_ws, size_t ws_size,
                              hipStream_t stream)
{
    const float* x     = (const float*)d_in[0];
    const float* s1k7  = (const float*)d_in[1];
    const float* s1k5  = (const float*)d_in[2];
    const float* s1k3  = (const float*)d_in[3];
    const float* s1g   = (const float*)d_in[5];
    const float* s1be  = (const float*)d_in[6];
    const float* s2k7  = (const float*)d_in[7];
    const float* s2k5  = (const float*)d_in[8];
    const float* s2k3  = (const float*)d_in[9];
    const float* s2g   = (const float*)d_in[11];
    const float* s2be  = (const float*)d_in[12];
    const float* s3k7  = (const float*)d_in[13];
    const float* s3k5  = (const float*)d_in[14];
    const float* s3k3  = (const float*)d_in[15];
    const float* s3g   = (const float*)d_in[17];
    const float* s3be  = (const float*)d_in[18];
    const float* outw  = (const float*)d_in[19];
    const float* outb  = (const float*)d_in[20];

    float* ws = (float*)d_ws;
    size_t off = 0;
    float* km1  = ws + off; off += 103 * 49 * 32;
    float* km2  = ws + off; off += 32 * 49 * 32;
    float* km3  = ws + off; off += 64 * 49 * 32;
    float* y1   = ws + off; off += 32 * HW;
    float* y2   = ws + off; off += 32 * HW;
    float* y3   = ws + off; off += 32 * HW;
    float* stats= ws + off; off += 192;   // sum1,sq1,sum2,sq2,sum3,sq3
    float* bn   = ws + off; off += 192;   // scl1,shf1,scl2,shf2,scl3,shf3
    float* pf   = ws + off; off += 118 * HW;
    float* cent = ws + off; off += 118 * 256;
    float* cnr  = ws + off; off += 119 * 256;
    float* cn2  = ws + off; off += 256;

    // partial conv planes (3 x 32 x HW = 6.3M floats) reuse the pf region,
    // which is dead until feat_kernel runs.
    float* part = pf;

    hipMemsetAsync(stats, 0, 192 * sizeof(float), stream);
    merge_kernel<<<(103 * 49 * 32 + 255) / 256, 256, 0, stream>>>(s1k7, s1k5, s1k3, km1, 103);
    merge_kernel<<<(32 * 49 * 32 + 255) / 256, 256, 0, stream>>>(s2k7, s2k5, s2k3, km2, 32);
    merge_kernel<<<(64 * 49 * 32 + 255) / 256, 256, 0, stream>>>(s3k7, s3k5, s3k3, km3, 64);

    conv7_kernel<<<dim3(256, 2, 3), 256, 0, stream>>>(x, 103, nullptr, nullptr,
                                                      nullptr, nullptr, nullptr,
                                                      km1, 103, part);
    reduce3_kernel<<<1024, 256, 0, stream>>>(part, y1, stats + 0, stats + 32);
    bnp_kernel<<<1, 32, 0, stream>>>(stats + 0, stats + 32, s1g, s1be, bn + 0, bn + 32);

    conv7_kernel<<<dim3(256, 2, 3), 256, 0, stream>>>(y1, 32, bn + 0, bn + 32,
                                                      nullptr, nullptr, nullptr,
                                                      km2, 32, part);
    reduce3_kernel<<<1024, 256, 0, stream>>>(part, y2, stats + 64, stats + 96);
    bnp_kernel<<<1, 32, 0, stream>>>(stats + 64, stats + 96, s2g, s2be, bn + 64, bn + 96);

    conv7_kernel<<<dim3(256, 2, 3), 256, 0, stream>>>(y1, 32, bn + 0, bn + 32,
                                                      y2, bn + 64, bn + 96,
                                                      km3, 64, part);
    reduce3_kernel<<<1024, 256, 0, stream>>>(part, y3, stats + 128, stats + 160);
    bnp_kernel<<<1, 32, 0, stream>>>(stats + 128, stats + 160, s3g, s3be, bn + 128, bn + 160);

    feat_kernel<<<256, 256, 0, stream>>>(y1, y2, y3, bn, outw, outb, x, pf);
    c0_kernel<<<118, 256, 0, stream>>>(pf, cent);
    cn2_kernel<<<1, 256, 0, stream>>>(cent, cn2);

    float* Q = (float*)d_out;
    for (int it = 0; it < 5; ++it) {
        dist_kernel<<<1024, 256, 0, stream>>>(cent, cn2, pf, Q);
        hipMemsetAsync(cnr, 0, 119 * 256 * sizeof(float), stream);
        cn_kernel<<<dim3(64, 4), 256, 0, stream>>>(Q, pf, cnr);
        upd_kernel<<<1, 256, 0, stream>>>(cnr, cent, cn2);
    }
    dist_kernel<<<1024, 256, 0, stream>>>(cent, cn2, pf, Q);
}

// Round 3
// 1590.524 us; speedup vs baseline: 2.4382x; 1.5505x over previous
//
#include <hip/hip_runtime.h>

#define HW 65536

typedef short bf16x8 __attribute__((ext_vector_type(8)));
typedef float f32x4 __attribute__((ext_vector_type(4)));
typedef unsigned short u16x8 __attribute__((ext_vector_type(8)));

__device__ inline unsigned short f2bf(float v) {
    unsigned u = __float_as_uint(v);
    unsigned r = (u + 0x7FFF + ((u >> 16) & 1)) >> 16;
    return (unsigned short)r;
}
__device__ inline float ubf(unsigned short h) {
    return __uint_as_float(((unsigned)h) << 16);
}

// ---------------------------------------------------------------------------
// Merge 7x7 + 5x5 + 3x3 kernels into one 7x7, layout [ci][49][32oc]
// ---------------------------------------------------------------------------
__global__ void merge_kernel(const float* __restrict__ k7, const float* __restrict__ k5,
                             const float* __restrict__ k3, float* __restrict__ km, int Cin)
{
    int idx = blockIdx.x * 256 + threadIdx.x;
    int total = Cin * 49 * 32;
    if (idx >= total) return;
    int oc = idx & 31;
    int kk = (idx >> 5) % 49;
    int ci = idx / (49 * 32);
    int ky = kk / 7, kx = kk % 7;
    float v = k7[(oc * Cin + ci) * 49 + kk];
    if (ky >= 1 && ky <= 5 && kx >= 1 && kx <= 5)
        v += k5[(oc * Cin + ci) * 25 + (ky - 1) * 5 + (kx - 1)];
    if (ky >= 2 && ky <= 4 && kx >= 2 && kx <= 4)
        v += k3[(oc * Cin + ci) * 9 + (ky - 2) * 3 + (kx - 2)];
    km[idx] = v;
}

// ---------------------------------------------------------------------------
// 7x7 SAME conv, cin split 3 ways -> partial planes (unchanged from R2)
// ---------------------------------------------------------------------------
__global__ __launch_bounds__(256) void conv7_kernel(
    const float* __restrict__ inA, int CA,
    const float* __restrict__ sclA, const float* __restrict__ shfA,
    const float* __restrict__ inB,
    const float* __restrict__ sclB, const float* __restrict__ shfB,
    const float* __restrict__ km, int Cin,
    float* __restrict__ part)
{
    __shared__ float tile[4 * 528];
    int t  = threadIdx.x;
    int tx = t & 15, ty = t >> 4;
    int bx = blockIdx.x & 15, by = blockIdx.x >> 4;
    int px0 = bx * 16, py0 = by * 16;
    int ocb = blockIdx.y * 16;
    int split = (Cin + 2) / 3;
    int cin0 = blockIdx.z * split;
    int cin1 = cin0 + split; if (cin1 > Cin) cin1 = Cin;

    float acc[16];
#pragma unroll
    for (int i = 0; i < 16; ++i) acc[i] = 0.f;

    for (int cc = cin0; cc < cin1; cc += 4) {
        __syncthreads();
        for (int i = t; i < 4 * 484; i += 256) {
            int ci = i / 484, r = i % 484;
            int ly = r / 22, lx = r % 22;
            int c = cc + ci;
            int gy = py0 + ly - 3, gx = px0 + lx - 3;
            float v = 0.f;
            if (c < cin1 && gy >= 0 && gy < 256 && gx >= 0 && gx < 256) {
                if (c < CA) {
                    v = inA[c * HW + gy * 256 + gx];
                    if (sclA) v = fmaxf(v * sclA[c] + shfA[c], 0.f);
                } else {
                    int c2 = c - CA;
                    v = inB[c2 * HW + gy * 256 + gx];
                    v = fmaxf(v * sclB[c2] + shfB[c2], 0.f);
                }
            }
            tile[ci * 528 + ly * 24 + lx] = v;
        }
        __syncthreads();
        int cmax = cin1 - cc; if (cmax > 4) cmax = 4;
        for (int ci = 0; ci < cmax; ++ci) {
            const float* wbase = km + (cc + ci) * 49 * 32 + ocb;
            const float* trow = tile + ci * 528;
#pragma unroll
            for (int ky = 0; ky < 7; ++ky) {
#pragma unroll
                for (int kx = 0; kx < 7; ++kx) {
                    float xv = trow[(ty + ky) * 24 + tx + kx];
                    const float* wk = wbase + (ky * 7 + kx) * 32;
#pragma unroll
                    for (int oc = 0; oc < 16; ++oc)
                        acc[oc] = fmaf(xv, wk[oc], acc[oc]);
                }
            }
        }
    }

    int n = (py0 + ty) * 256 + px0 + tx;
    float* o = part + (size_t)blockIdx.z * 32 * HW;
#pragma unroll
    for (int oc = 0; oc < 16; ++oc)
        o[(ocb + oc) * HW + n] = acc[oc];
}

// ---------------------------------------------------------------------------
// Sum 3 partial planes -> y, accumulate per-channel sum/sumsq
// ---------------------------------------------------------------------------
__global__ __launch_bounds__(256) void reduce3_kernel(
    const float* __restrict__ part, float* __restrict__ y,
    float* __restrict__ ssum, float* __restrict__ ssq)
{
    int b = blockIdx.x;
    int c = b >> 5, seg = b & 31;
    int base = c * HW + seg * 2048 + threadIdx.x * 8;

    float s = 0.f, q = 0.f;
#pragma unroll
    for (int h = 0; h < 2; ++h) {
        int o = base + h * 4;
        float4 a0 = *(const float4*)&part[o];
        float4 a1 = *(const float4*)&part[32 * HW + o];
        float4 a2 = *(const float4*)&part[64 * HW + o];
        float4 v;
        v.x = a0.x + a1.x + a2.x;
        v.y = a0.y + a1.y + a2.y;
        v.z = a0.z + a1.z + a2.z;
        v.w = a0.w + a1.w + a2.w;
        *(float4*)&y[o] = v;
        s += v.x + v.y + v.z + v.w;
        q = fmaf(v.x, v.x, q); q = fmaf(v.y, v.y, q);
        q = fmaf(v.z, v.z, q); q = fmaf(v.w, v.w, q);
    }
#pragma unroll
    for (int d = 32; d >= 1; d >>= 1) {
        s += __shfl_down(s, d);
        q += __shfl_down(q, d);
    }
    __shared__ float ls[4], lq[4];
    int w = threadIdx.x >> 6;
    if ((threadIdx.x & 63) == 0) { ls[w] = s; lq[w] = q; }
    __syncthreads();
    if (threadIdx.x == 0) {
        float S = ls[0] + ls[1] + ls[2] + ls[3];
        float Qq = lq[0] + lq[1] + lq[2] + lq[3];
        atomicAdd(&ssum[c], S);
        atomicAdd(&ssq[c], Qq);
    }
}

__global__ void bnp_kernel(const float* __restrict__ ssum, const float* __restrict__ ssq,
                           const float* __restrict__ g, const float* __restrict__ beta,
                           float* __restrict__ scl, float* __restrict__ shf)
{
    int c = threadIdx.x;
    float mu  = ssum[c] * (1.f / 65536.f);
    float var = ssq[c] * (1.f / 65536.f) - mu * mu;
    float s = g[c] * rsqrtf(var + 1e-5f);
    scl[c] = s;
    shf[c] = beta[c] - mu * s;
}

// ---------------------------------------------------------------------------
// 1x1 conv (96->15) + ReLU; assemble pf in TWO bf16 layouts:
//   pf_T [n][128]: hi+lo planes; ch 0..117 data, 118..126 = 0, 127 = 1.0/0
//   pf_c [c][n]:   hi plane only; ch 118 = 1.0, 119..127 = 0
// ---------------------------------------------------------------------------
__global__ __launch_bounds__(256) void feat_kernel(
    const float* __restrict__ y1, const float* __restrict__ y2, const float* __restrict__ y3,
    const float* __restrict__ bn,
    const float* __restrict__ w, const float* __restrict__ b,
    const float* __restrict__ x,
    unsigned short* __restrict__ pfTh, unsigned short* __restrict__ pfTl,
    unsigned short* __restrict__ pfch)
{
    int n = blockIdx.x * 256 + threadIdx.x;
    float facc[15];
#pragma unroll
    for (int oc = 0; oc < 15; ++oc) facc[oc] = b[oc];

    const float* srcs[3] = {y1, y2, y3};
#pragma unroll
    for (int s = 0; s < 3; ++s) {
        const float* src = srcs[s];
        const float* scl = bn + s * 64;
        const float* shf = scl + 32;
        for (int c = 0; c < 32; ++c) {
            float v = fmaxf(src[c * HW + n] * scl[c] + shf[c], 0.f);
#pragma unroll
            for (int oc = 0; oc < 15; ++oc)
                facc[oc] = fmaf(v, w[oc * 96 + s * 32 + c], facc[oc]);
        }
    }
#pragma unroll
    for (int oc = 0; oc < 15; ++oc) facc[oc] = fmaxf(facc[oc], 0.f);

    for (int c0 = 0; c0 < 128; c0 += 8) {
        unsigned short h[8], lo[8];
#pragma unroll
        for (int j = 0; j < 8; ++j) {
            int c = c0 + j;
            float val;
            if (c < 15) val = facc[c];
            else if (c < 118) val = x[(size_t)(c - 15) * HW + n];
            else if (c == 127) val = 1.f;
            else val = 0.f;
            unsigned short hh = f2bf(val);
            h[j] = hh;
            lo[j] = f2bf(val - ubf(hh));
        }
        uint4 ph, pl;
        ph.x = (unsigned)h[0] | ((unsigned)h[1] << 16);
        ph.y = (unsigned)h[2] | ((unsigned)h[3] << 16);
        ph.z = (unsigned)h[4] | ((unsigned)h[5] << 16);
        ph.w = (unsigned)h[6] | ((unsigned)h[7] << 16);
        pl.x = (unsigned)lo[0] | ((unsigned)lo[1] << 16);
        pl.y = (unsigned)lo[2] | ((unsigned)lo[3] << 16);
        pl.z = (unsigned)lo[4] | ((unsigned)lo[5] << 16);
        pl.w = (unsigned)lo[6] | ((unsigned)lo[7] << 16);
        *(uint4*)(pfTh + (size_t)n * 128 + c0) = ph;
        *(uint4*)(pfTl + (size_t)n * 128 + c0) = pl;
#pragma unroll
        for (int j = 0; j < 8; ++j) {
            int c = c0 + j;
            unsigned short pv = (c < 118) ? h[j] : ((c == 118) ? (unsigned short)0x3F80 : (unsigned short)0);
            pfch[(size_t)c * HW + n] = pv;
        }
    }
}

// ---------------------------------------------------------------------------
// c0: per-superpixel channel sums (over 256 pixels) -> cn_fin[s][128]
// ---------------------------------------------------------------------------
__global__ __launch_bounds__(256) void c0_kernel(
    const unsigned short* __restrict__ pfTh, const unsigned short* __restrict__ pfTl,
    float* __restrict__ cn_fin)
{
    int s = blockIdx.x;
    int sy = s >> 4, sx = s & 15;
    int t = threadIdx.x;
    int xx = t >> 4;
    int cs = (t & 15) * 8;

    float acc[8];
#pragma unroll
    for (int j = 0; j < 8; ++j) acc[j] = 0.f;

    for (int yy = 0; yy < 16; ++yy) {
        int n = (sy * 16 + yy) * 256 + sx * 16 + xx;
        u16x8 h = *(const u16x8*)(pfTh + (size_t)n * 128 + cs);
        u16x8 l = *(const u16x8*)(pfTl + (size_t)n * 128 + cs);
#pragma unroll
        for (int j = 0; j < 8; ++j)
            acc[j] += ubf(h[j]) + ubf(l[j]);
    }
#pragma unroll
    for (int j = 0; j < 8; ++j) {
        acc[j] += __shfl_xor(acc[j], 16);
        acc[j] += __shfl_xor(acc[j], 32);
    }
    __shared__ float red[4][128];
    int w = t >> 6;
    if ((t & 63) < 16) {
#pragma unroll
        for (int j = 0; j < 8; ++j)
            red[w][(t & 15) * 8 + j] = acc[j];
    }
    __syncthreads();
    if (t < 128)
        cn_fin[s * 128 + t] = red[0][t] + red[1][t] + red[2][t] + red[3][t];
}

// ---------------------------------------------------------------------------
// prep: centroids -> chi_T/clo_T [s][128] bf16 hi/lo; slot 127 = -0.5*|c|^2
// mode 0: cent = cn_fin * scale0 (block means); mode 1: / (qsum + eps)
// ---------------------------------------------------------------------------
__global__ void prep_kernel(const float* __restrict__ cn_fin,
                            unsigned short* __restrict__ chiT, unsigned short* __restrict__ cloT,
                            float scale0, int use_qsum)
{
    int s = threadIdx.x;
    float inv = use_qsum ? 1.f / (cn_fin[s * 128 + 118] + 1e-8f) : scale0;
    float a = 0.f;
    for (int c = 0; c < 118; ++c) {
        float v = cn_fin[s * 128 + c] * inv;
        a = fmaf(v, v, a);
        unsigned short h = f2bf(v);
        chiT[s * 128 + c] = h;
        cloT[s * 128 + c] = f2bf(v - ubf(h));
    }
    for (int c = 118; c < 127; ++c) { chiT[s * 128 + c] = 0; cloT[s * 128 + c] = 0; }
    float m2 = -0.5f * a;
    unsigned short h = f2bf(m2);
    chiT[s * 128 + 127] = h;
    cloT[s * 128 + 127] = f2bf(m2 - ubf(h));
}

// ---------------------------------------------------------------------------
// dist: Q[s,n] = softmax_s( 2*(cent . pf - 0.5*cn2) )  via MFMA 16x16x32 bf16
// 3 phases: Ah*Bh + Al*Bh + Ah*Bl  (hi/lo split ~ fp32 logits)
// Block: 256 thr = 4 waves; wave: all 256 s x 16 n. Grid: 1024.
// Softmax in-register: per-lane 64 logits + shfl_xor(16,32).
// ---------------------------------------------------------------------------
__global__ __launch_bounds__(256) void dist_kernel(
    const unsigned short* __restrict__ chiT, const unsigned short* __restrict__ cloT,
    const unsigned short* __restrict__ pfTh, const unsigned short* __restrict__ pfTl,
    unsigned short* __restrict__ qh, float* __restrict__ qf, int final_mode)
{
    int t = threadIdx.x;
    int w = t >> 6, l = t & 63;
    int n0 = blockIdx.x * 64 + w * 16;
    int lc = l & 15;          // col within tile (n for B/D, row for A)
    int lg = l >> 4;          // k-group

    f32x4 acc[16];
#pragma unroll
    for (int i = 0; i < 16; ++i)
#pragma unroll
        for (int j = 0; j < 4; ++j) acc[i][j] = 0.f;

#pragma unroll
    for (int phse = 0; phse < 3; ++phse) {
        const unsigned short* Ap = (phse == 1) ? cloT : chiT;
        const unsigned short* Bp = (phse == 2) ? pfTl : pfTh;
#pragma unroll
        for (int ks = 0; ks < 4; ++ks) {
            int kb = ks * 32 + 8 * lg;
            bf16x8 bfr = *(const bf16x8*)(Bp + (size_t)(n0 + lc) * 128 + kb);
#pragma unroll
            for (int st = 0; st < 16; ++st) {
                bf16x8 afr = *(const bf16x8*)(Ap + (size_t)(st * 16 + lc) * 128 + kb);
                acc[st] = __builtin_amdgcn_mfma_f32_16x16x32_bf16(afr, bfr, acc[st], 0, 0, 0);
            }
        }
    }

    // softmax over s: per lane 64 values; partner lanes via xor 16/32
    float m = -1e30f;
#pragma unroll
    for (int st = 0; st < 16; ++st)
#pragma unroll
        for (int r = 0; r < 4; ++r) m = fmaxf(m, acc[st][r]);
    m = fmaxf(m, __shfl_xor(m, 16));
    m = fmaxf(m, __shfl_xor(m, 32));

    float ssum = 0.f;
#pragma unroll
    for (int st = 0; st < 16; ++st)
#pragma unroll
        for (int r = 0; r < 4; ++r) {
            float e = __expf(2.f * (acc[st][r] - m));
            acc[st][r] = e;
            ssum += e;
        }
    ssum += __shfl_xor(ssum, 16);
    ssum += __shfl_xor(ssum, 32);
    float inv = 1.f / ssum;

    int n = n0 + lc;
    if (!final_mode) {
#pragma unroll
        for (int st = 0; st < 16; ++st)
#pragma unroll
            for (int r = 0; r < 4; ++r) {
                int s = st * 16 + lg * 4 + r;
                qh[(size_t)s * HW + n] = f2bf(acc[st][r] * inv);
            }
    } else {
#pragma unroll
        for (int st = 0; st < 16; ++st)
#pragma unroll
            for (int r = 0; r < 4; ++r) {
                int s = st * 16 + lg * 4 + r;
                qf[(size_t)s * HW + n] = acc[st][r] * inv;
            }
    }
}

// ---------------------------------------------------------------------------
// cn: D[s,c] = sum_n Q[s,n]*pf[c,n]  (single bf16 phase; K=65536 averages out
// rounding). Block: 512 thr = 8 waves (wave = c-tile of 16); K-slice = 512 n.
// Grid: 128. Writes partials; reduce_cn sums.
// ---------------------------------------------------------------------------
__global__ __launch_bounds__(512) void cn_kernel(
    const unsigned short* __restrict__ qh, const unsigned short* __restrict__ pfch,
    float* __restrict__ cn_part)
{
    int t = threadIdx.x;
    int w = t >> 6, l = t & 63;
    int lc = l & 15, lg = l >> 4;
    int n0 = blockIdx.x * 512;

    f32x4 acc[16];
#pragma unroll
    for (int i = 0; i < 16; ++i)
#pragma unroll
        for (int j = 0; j < 4; ++j) acc[i][j] = 0.f;

    for (int ks = 0; ks < 16; ++ks) {
        int nb = n0 + ks * 32 + 8 * lg;
        bf16x8 bfr = *(const bf16x8*)(pfch + (size_t)(w * 16 + lc) * HW + nb);
#pragma unroll
        for (int st = 0; st < 16; ++st) {
            bf16x8 afr = *(const bf16x8*)(qh + (size_t)(st * 16 + lc) * HW + nb);
            acc[st] = __builtin_amdgcn_mfma_f32_16x16x32_bf16(afr, bfr, acc[st], 0, 0, 0);
        }
    }

    float* out = cn_part + (size_t)blockIdx.x * 32768;
#pragma unroll
    for (int st = 0; st < 16; ++st)
#pragma unroll
        for (int r = 0; r < 4; ++r) {
            int s = st * 16 + lg * 4 + r;
            out[s * 128 + w * 16 + lc] = acc[st][r];
        }
}

__global__ void reduce_cn(const float* __restrict__ cn_part, float* __restrict__ cn_fin)
{
    int o = blockIdx.x * 256 + threadIdx.x;   // 32768 outputs
    float a = 0.f;
    for (int k = 0; k < 128; ++k) a += cn_part[(size_t)k * 32768 + o];
    cn_fin[o] = a;
}

// ---------------------------------------------------------------------------
extern "C" void kernel_launch(void* const* d_in, const int* in_sizes, int n_in,
                              void* d_out, int out_size, void* d_ws, size_t ws_size,
                              hipStream_t stream)
{
    const float* x     = (const float*)d_in[0];
    const float* s1k7  = (const float*)d_in[1];
    const float* s1k5  = (const float*)d_in[2];
    const float* s1k3  = (const float*)d_in[3];
    const float* s1g   = (const float*)d_in[5];
    const float* s1be  = (const float*)d_in[6];
    const float* s2k7  = (const float*)d_in[7];
    const float* s2k5  = (const float*)d_in[8];
    const float* s2k3  = (const float*)d_in[9];
    const float* s2g   = (const float*)d_in[11];
    const float* s2be  = (const float*)d_in[12];
    const float* s3k7  = (const float*)d_in[13];
    const float* s3k5  = (const float*)d_in[14];
    const float* s3k3  = (const float*)d_in[15];
    const float* s3g   = (const float*)d_in[17];
    const float* s3be  = (const float*)d_in[18];
    const float* outw  = (const float*)d_in[19];
    const float* outb  = (const float*)d_in[20];

    float* ws = (float*)d_ws;
    size_t off = 0;
    float* km1   = ws + off; off += 103 * 49 * 32;
    float* km2   = ws + off; off += 32 * 49 * 32;
    float* km3   = ws + off; off += 64 * 49 * 32;
    float* stats = ws + off; off += 192;
    float* bn    = ws + off; off += 192;
    float* cn_fin= ws + off; off += 32768;
    float* y1    = ws + off; off += 32 * HW;
    float* y2    = ws + off; off += 32 * HW;
    float* y3    = ws + off; off += 32 * HW;
    float* R     = ws + off; off += 12 * 1024 * 1024;   // 48 MB region
    unsigned short* chiT = (unsigned short*)(ws + off); off += 16384;
    unsigned short* cloT = (unsigned short*)(ws + off); off += 16384;

    // region aliases
    float* part = R;                                    // 3x32xHW during convs
    unsigned short* pfTh = (unsigned short*)R;          // [65536][128]
    unsigned short* pfTl = pfTh + (size_t)HW * 128;     // [65536][128]
    unsigned short* pfch = pfTl + (size_t)HW * 128;     // [128][65536]
    float* cn_part = y1;                                // 128*32768 floats = y1+y2

    unsigned short* qh = (unsigned short*)d_out;        // bf16 Q during iterations
    float* qf = (float*)d_out;

    hipMemsetAsync(stats, 0, 192 * sizeof(float), stream);
    merge_kernel<<<(103 * 49 * 32 + 255) / 256, 256, 0, stream>>>(s1k7, s1k5, s1k3, km1, 103);
    merge_kernel<<<(32 * 49 * 32 + 255) / 256, 256, 0, stream>>>(s2k7, s2k5, s2k3, km2, 32);
    merge_kernel<<<(64 * 49 * 32 + 255) / 256, 256, 0, stream>>>(s3k7, s3k5, s3k3, km3, 64);

    conv7_kernel<<<dim3(256, 2, 3), 256, 0, stream>>>(x, 103, nullptr, nullptr,
                                                      nullptr, nullptr, nullptr,
                                                      km1, 103, part);
    reduce3_kernel<<<1024, 256, 0, stream>>>(part, y1, stats + 0, stats + 32);
    bnp_kernel<<<1, 32, 0, stream>>>(stats + 0, stats + 32, s1g, s1be, bn + 0, bn + 32);

    conv7_kernel<<<dim3(256, 2, 3), 256, 0, stream>>>(y1, 32, bn + 0, bn + 32,
                                                      nullptr, nullptr, nullptr,
                                                      km2, 32, part);
    reduce3_kernel<<<1024, 256, 0, stream>>>(part, y2, stats + 64, stats + 96);
    bnp_kernel<<<1, 32, 0, stream>>>(stats + 64, stats + 96, s2g, s2be, bn + 64, bn + 96);

    conv7_kernel<<<dim3(256, 2, 3), 256, 0, stream>>>(y1, 32, bn + 0, bn + 32,
                                                      y2, bn + 64, bn + 96,
                                                      km3, 64, part);
    reduce3_kernel<<<1024, 256, 0, stream>>>(part, y3, stats + 128, stats + 160);
    bnp_kernel<<<1, 32, 0, stream>>>(stats + 128, stats + 160, s3g, s3be, bn + 128, bn + 160);

    feat_kernel<<<256, 256, 0, stream>>>(y1, y2, y3, bn, outw, outb, x, pfTh, pfTl, pfch);
    c0_kernel<<<256, 256, 0, stream>>>(pfTh, pfTl, cn_fin);
    prep_kernel<<<1, 256, 0, stream>>>(cn_fin, chiT, cloT, 1.f / 256.f, 0);

    for (int it = 0; it < 5; ++it) {
        dist_kernel<<<1024, 256, 0, stream>>>(chiT, cloT, pfTh, pfTl, qh, qf, 0);
        cn_kernel<<<128, 512, 0, stream>>>(qh, pfch, cn_part);
        reduce_cn<<<128, 256, 0, stream>>>(cn_part, cn_fin);
        prep_kernel<<<1, 256, 0, stream>>>(cn_fin, chiT, cloT, 0.f, 1);
    }
    dist_kernel<<<1024, 256, 0, stream>>>(chiT, cloT, pfTh, pfTl, qh, qf, 1);
}

// Round 5
// 1281.899 us; speedup vs baseline: 3.0252x; 1.2408x over previous
//
#include <hip/hip_runtime.h>

#define HW 65536

typedef short bf16x8 __attribute__((ext_vector_type(8)));
typedef float f32x4 __attribute__((ext_vector_type(4)));
typedef unsigned short u16x8 __attribute__((ext_vector_type(8)));

__device__ inline unsigned short f2bf(float v) {
    unsigned u = __float_as_uint(v);
    unsigned r = (u + 0x7FFF + ((u >> 16) & 1)) >> 16;
    return (unsigned short)r;
}
__device__ inline float ubf(unsigned short h) {
    return __uint_as_float(((unsigned)h) << 16);
}
__device__ inline uint4 pack8(const unsigned short* p) {
    uint4 u;
    u.x = (unsigned)p[0] | ((unsigned)p[1] << 16);
    u.y = (unsigned)p[2] | ((unsigned)p[3] << 16);
    u.z = (unsigned)p[4] | ((unsigned)p[5] << 16);
    u.w = (unsigned)p[6] | ((unsigned)p[7] << 16);
    return u;
}

// ---------------------------------------------------------------------------
// Merge 7/5/3 kernels into one 7x7 and write bf16 hi/lo in [tap][oc][ci] layout
// ---------------------------------------------------------------------------
__global__ void wmerge_kernel(const float* __restrict__ k7, const float* __restrict__ k5,
                              const float* __restrict__ k3, int Cin, int Cpw,
                              unsigned short* __restrict__ wTh, unsigned short* __restrict__ wTl)
{
    int idx = blockIdx.x * 256 + threadIdx.x;
    int total = 49 * 32 * Cpw;
    if (idx >= total) return;
    int ci = idx % Cpw;
    int oc = (idx / Cpw) & 31;
    int tap = idx / (Cpw * 32);
    int ky = tap / 7, kx = tap % 7;
    float v = 0.f;
    if (ci < Cin) {
        v = k7[(oc * Cin + ci) * 49 + tap];
        if (ky >= 1 && ky <= 5 && kx >= 1 && kx <= 5)
            v += k5[(oc * Cin + ci) * 25 + (ky - 1) * 5 + (kx - 1)];
        if (ky >= 2 && ky <= 4 && kx >= 2 && kx <= 4)
            v += k3[(oc * Cin + ci) * 9 + (ky - 2) * 3 + (kx - 2)];
    }
    unsigned short h = f2bf(v);
    wTh[idx] = h;
    wTl[idx] = f2bf(v - ubf(h));
}

// ---------------------------------------------------------------------------
// x [103][HW] fp32 -> xT [n][128] bf16 hi/lo (slots 0..102 = x, 103..127 = 0)
// and pfch [c][HW] bf16 hi (rows 0..102)
// ---------------------------------------------------------------------------
__global__ __launch_bounds__(256) void transpose_kernel(
    const float* __restrict__ x,
    unsigned short* __restrict__ xTh, unsigned short* __restrict__ xTl,
    unsigned short* __restrict__ pfch)
{
    __shared__ float buf[64 * 105];
    int t = threadIdx.x;
    int px0 = blockIdx.x * 64;
    for (int i = t; i < 103 * 64; i += 256) {
        int c = i >> 6, lane = i & 63;
        float v = x[(size_t)c * HW + px0 + lane];
        buf[lane * 105 + c] = v;
        pfch[(size_t)c * HW + px0 + lane] = f2bf(v);
    }
    __syncthreads();
    int px = t >> 2, seg = t & 3;
    unsigned short h[32], l[32];
#pragma unroll
    for (int j = 0; j < 32; ++j) {
        int c = seg * 32 + j;
        float v = (c < 103) ? buf[px * 105 + c] : 0.f;
        h[j] = f2bf(v);
        l[j] = f2bf(v - ubf(h[j]));
    }
    size_t base = (size_t)(px0 + px) * 128 + seg * 32;
#pragma unroll
    for (int k = 0; k < 4; ++k) {
        *(uint4*)(xTh + base + k * 8) = pack8(h + k * 8);
        *(uint4*)(xTl + base + k * 8) = pack8(l + k * 8);
    }
}

// ---------------------------------------------------------------------------
// Implicit-GEMM 7x7 conv via MFMA 16x16x32 bf16, 3-phase hi/lo.
// act: channel-last [n][Cs] hi/lo. weights: [tap][32oc][Cpw] hi/lo.
// Block: 256 thr = 4 waves; output 8 y-rows x 16 x x 32 oc. Grid 512.
// ---------------------------------------------------------------------------
__global__ __launch_bounds__(256) void convm_kernel(
    const unsigned short* __restrict__ actH, const unsigned short* __restrict__ actL,
    int Cs,
    const unsigned short* __restrict__ wTh, const unsigned short* __restrict__ wTl,
    int Cpw, int nch,
    float* __restrict__ yraw)
{
    __shared__ __align__(16) unsigned short sH[14 * 22 * 32];
    __shared__ __align__(16) unsigned short sL[14 * 22 * 32];
    int t = threadIdx.x;
    int w = t >> 6, l = t & 63;
    int lc = l & 15, lg = l >> 4;
    int bx = blockIdx.x & 15, byy = blockIdx.x >> 4;
    int x0 = bx * 16, y0 = byy * 8;

    f32x4 acc[2][2];
#pragma unroll
    for (int a = 0; a < 2; ++a)
#pragma unroll
        for (int b = 0; b < 2; ++b)
#pragma unroll
            for (int r = 0; r < 4; ++r) acc[a][b][r] = 0.f;

    for (int ch = 0; ch < nch; ++ch) {
        int ci0 = ch * 32;
        __syncthreads();
        for (int i = t; i < 2464; i += 256) {
            int pl = (i >= 1232) ? 1 : 0;
            int j = pl ? i - 1232 : i;
            int row = j / 88;
            int rem = j - row * 88;
            int px = rem >> 2, q = rem & 3;
            int gy = y0 - 3 + row, gx = x0 - 3 + px;
            uint4 v = {0u, 0u, 0u, 0u};
            if (gy >= 0 && gy < 256 && gx >= 0 && gx < 256) {
                const unsigned short* src = pl ? actL : actH;
                v = *(const uint4*)(src + (size_t)(gy * 256 + gx) * Cs + ci0 + q * 8);
            }
            unsigned short* dst = pl ? sL : sH;
            *(uint4*)(dst + row * 704 + px * 32 + q * 8) = v;
        }
        __syncthreads();

        int wfoff = lc * Cpw + ci0 + 8 * lg;
        bf16x8 ah0 = *(const bf16x8*)(wTh + wfoff);
        bf16x8 ah1 = *(const bf16x8*)(wTh + wfoff + 16 * Cpw);
        bf16x8 al0 = *(const bf16x8*)(wTl + wfoff);
        bf16x8 al1 = *(const bf16x8*)(wTl + wfoff + 16 * Cpw);

        for (int tap = 0; tap < 49; ++tap) {
            bf16x8 nh0, nh1, nl0, nl1;
            if (tap < 48) {
                int noff = (tap + 1) * 32 * Cpw + wfoff;
                nh0 = *(const bf16x8*)(wTh + noff);
                nh1 = *(const bf16x8*)(wTh + noff + 16 * Cpw);
                nl0 = *(const bf16x8*)(wTl + noff);
                nl1 = *(const bf16x8*)(wTl + noff + 16 * Cpw);
            }
            int ky = tap / 7;
            int kx = tap - ky * 7;
#pragma unroll
            for (int rr = 0; rr < 2; ++rr) {
                int row = w * 2 + rr + ky;
                int off = row * 704 + (lc + kx) * 32 + lg * 8;
                bf16x8 bh = *(const bf16x8*)(sH + off);
                bf16x8 bl = *(const bf16x8*)(sL + off);
                acc[0][rr] = __builtin_amdgcn_mfma_f32_16x16x32_bf16(ah0, bh, acc[0][rr], 0, 0, 0);
                acc[0][rr] = __builtin_amdgcn_mfma_f32_16x16x32_bf16(al0, bh, acc[0][rr], 0, 0, 0);
                acc[0][rr] = __builtin_amdgcn_mfma_f32_16x16x32_bf16(ah0, bl, acc[0][rr], 0, 0, 0);
                acc[1][rr] = __builtin_amdgcn_mfma_f32_16x16x32_bf16(ah1, bh, acc[1][rr], 0, 0, 0);
                acc[1][rr] = __builtin_amdgcn_mfma_f32_16x16x32_bf16(al1, bh, acc[1][rr], 0, 0, 0);
                acc[1][rr] = __builtin_amdgcn_mfma_f32_16x16x32_bf16(ah1, bl, acc[1][rr], 0, 0, 0);
            }
            if (tap < 48) { ah0 = nh0; ah1 = nh1; al0 = nl0; al1 = nl1; }
        }
    }

#pragma unroll
    for (int ot = 0; ot < 2; ++ot)
#pragma unroll
        for (int rr = 0; rr < 2; ++rr) {
            int n = (y0 + w * 2 + rr) * 256 + x0 + lc;
#pragma unroll
            for (int r = 0; r < 4; ++r) {
                int oc = ot * 16 + lg * 4 + r;
                yraw[(size_t)oc * HW + n] = acc[ot][rr][r];
            }
        }
}

// ---------------------------------------------------------------------------
// per-channel sum/sumsq of yraw
// ---------------------------------------------------------------------------
__global__ __launch_bounds__(256) void stats_kernel(
    const float* __restrict__ yraw, float* __restrict__ ssum, float* __restrict__ ssq)
{
    int c = blockIdx.x >> 5, seg = blockIdx.x & 31;
    int base = c * HW + seg * 2048 + threadIdx.x * 8;
    float4 a0 = *(const float4*)&yraw[base];
    float4 a1 = *(const float4*)&yraw[base + 4];
    float s = a0.x + a0.y + a0.z + a0.w + a1.x + a1.y + a1.z + a1.w;
    float q = a0.x * a0.x + a0.y * a0.y + a0.z * a0.z + a0.w * a0.w
            + a1.x * a1.x + a1.y * a1.y + a1.z * a1.z + a1.w * a1.w;
#pragma unroll
    for (int d = 32; d >= 1; d >>= 1) {
        s += __shfl_down(s, d);
        q += __shfl_down(q, d);
    }
    __shared__ float ls[4], lq[4];
    int w = threadIdx.x >> 6;
    if ((threadIdx.x & 63) == 0) { ls[w] = s; lq[w] = q; }
    __syncthreads();
    if (threadIdx.x == 0) {
        atomicAdd(&ssum[c], ls[0] + ls[1] + ls[2] + ls[3]);
        atomicAdd(&ssq[c], lq[0] + lq[1] + lq[2] + lq[3]);
    }
}

__global__ void bnp_kernel(const float* __restrict__ ssum, const float* __restrict__ ssq,
                           const float* __restrict__ g, const float* __restrict__ beta,
                           float* __restrict__ scl, float* __restrict__ shf)
{
    int c = threadIdx.x;
    float mu  = ssum[c] * (1.f / 65536.f);
    float var = ssq[c] * (1.f / 65536.f) - mu * mu;
    float s = g[c] * rsqrtf(var + 1e-5f);
    scl[c] = s;
    shf[c] = beta[c] - mu * s;
}

// ---------------------------------------------------------------------------
// BN + ReLU + write channel-last bf16 hi/lo
// ---------------------------------------------------------------------------
__global__ __launch_bounds__(256) void bna_kernel(
    const float* __restrict__ yraw, const float* __restrict__ scl, const float* __restrict__ shf,
    unsigned short* __restrict__ aH, unsigned short* __restrict__ aL, int Cs, int slot0)
{
    int t = threadIdx.x;
    int lane = t & 63, cg = t >> 6;
    int px = blockIdx.x * 64 + lane;
    unsigned short h[8], l[8];
#pragma unroll
    for (int j = 0; j < 8; ++j) {
        int c = cg * 8 + j;
        float v = fmaxf(yraw[(size_t)c * HW + px] * scl[c] + shf[c], 0.f);
        h[j] = f2bf(v);
        l[j] = f2bf(v - ubf(h[j]));
    }
    *(uint4*)(aH + (size_t)px * Cs + slot0 + cg * 8) = pack8(h);
    *(uint4*)(aL + (size_t)px * Cs + slot0 + cg * 8) = pack8(l);
}

// ---------------------------------------------------------------------------
// 1x1 conv (96->15) + ReLU from channel-last activations; writes pf slots
// 103..127 of xT (hi/lo) and pfch rows 103..127.
// ---------------------------------------------------------------------------
__global__ __launch_bounds__(256) void feat_kernel(
    const unsigned short* __restrict__ a12H, const unsigned short* __restrict__ a12L,
    const unsigned short* __restrict__ a3H, const unsigned short* __restrict__ a3L,
    const float* __restrict__ w, const float* __restrict__ b,
    unsigned short* __restrict__ xTh, unsigned short* __restrict__ xTl,
    unsigned short* __restrict__ pfch)
{
    int n = blockIdx.x * 256 + threadIdx.x;
    float facc[15];
#pragma unroll
    for (int oc = 0; oc < 15; ++oc) facc[oc] = b[oc];

#pragma unroll
    for (int k = 0; k < 12; ++k) {
        uint4 uh, ul;
        if (k < 8) {
            uh = *(const uint4*)(a12H + (size_t)n * 64 + k * 8);
            ul = *(const uint4*)(a12L + (size_t)n * 64 + k * 8);
        } else {
            uh = *(const uint4*)(a3H + (size_t)n * 32 + (k - 8) * 8);
            ul = *(const uint4*)(a3L + (size_t)n * 32 + (k - 8) * 8);
        }
        unsigned hw_[4] = {uh.x, uh.y, uh.z, uh.w};
        unsigned lw_[4] = {ul.x, ul.y, ul.z, ul.w};
#pragma unroll
        for (int j = 0; j < 8; ++j) {
            unsigned short hh = (unsigned short)(hw_[j >> 1] >> ((j & 1) * 16));
            unsigned short ll = (unsigned short)(lw_[j >> 1] >> ((j & 1) * 16));
            float av = ubf(hh) + ubf(ll);
#pragma unroll
            for (int oc = 0; oc < 15; ++oc)
                facc[oc] = fmaf(av, w[oc * 96 + k * 8 + j], facc[oc]);
        }
    }
    unsigned short fh[16], fl[16];
#pragma unroll
    for (int oc = 0; oc < 15; ++oc) {
        float v = fmaxf(facc[oc], 0.f);
        fh[oc] = f2bf(v);
        fl[oc] = f2bf(v - ubf(fh[oc]));
    }
    fh[15] = 0; fl[15] = 0;

    size_t base = (size_t)n * 128;
    uint4 h0 = *(const uint4*)(xTh + base + 96);
    uint4 l0 = *(const uint4*)(xTl + base + 96);
    h0.w = (h0.w & 0xFFFFu) | ((unsigned)fh[0] << 16);
    l0.w = (l0.w & 0xFFFFu) | ((unsigned)fl[0] << 16);
    *(uint4*)(xTh + base + 96) = h0;
    *(uint4*)(xTl + base + 96) = l0;
    *(uint4*)(xTh + base + 104) = pack8(fh + 1);
    *(uint4*)(xTl + base + 104) = pack8(fl + 1);
    unsigned short t2h[8], t2l[8];
#pragma unroll
    for (int j = 0; j < 8; ++j) {
        t2h[j] = (j < 6) ? fh[9 + j] : (unsigned short)0;
        t2l[j] = (j < 6) ? fl[9 + j] : (unsigned short)0;
    }
    *(uint4*)(xTh + base + 112) = pack8(t2h);
    *(uint4*)(xTl + base + 112) = pack8(t2l);
    unsigned short t3h[8] = {0, 0, 0, 0, 0, 0, 0, 0x3F80};
    unsigned short t3l[8] = {0, 0, 0, 0, 0, 0, 0, 0};
    *(uint4*)(xTh + base + 120) = pack8(t3h);
    *(uint4*)(xTl + base + 120) = pack8(t3l);

#pragma unroll
    for (int k2 = 0; k2 < 15; ++k2)
        pfch[(size_t)(103 + k2) * HW + n] = fh[k2];
    pfch[(size_t)118 * HW + n] = 0x3F80;
#pragma unroll
    for (int c = 119; c < 128; ++c)
        pfch[(size_t)c * HW + n] = 0;
}

// ---------------------------------------------------------------------------
// c0: per-superpixel channel sums -> cn_fin[s][128]
// ---------------------------------------------------------------------------
__global__ __launch_bounds__(256) void c0_kernel(
    const unsigned short* __restrict__ pfTh, const unsigned short* __restrict__ pfTl,
    float* __restrict__ cn_fin)
{
    int s = blockIdx.x;
    int sy = s >> 4, sx = s & 15;
    int t = threadIdx.x;
    int xx = t >> 4;
    int cs = (t & 15) * 8;

    float acc[8];
#pragma unroll
    for (int j = 0; j < 8; ++j) acc[j] = 0.f;

    for (int yy = 0; yy < 16; ++yy) {
        int n = (sy * 16 + yy) * 256 + sx * 16 + xx;
        u16x8 h = *(const u16x8*)(pfTh + (size_t)n * 128 + cs);
        u16x8 l = *(const u16x8*)(pfTl + (size_t)n * 128 + cs);
#pragma unroll
        for (int j = 0; j < 8; ++j)
            acc[j] += ubf(h[j]) + ubf(l[j]);
    }
#pragma unroll
    for (int j = 0; j < 8; ++j) {
        acc[j] += __shfl_xor(acc[j], 16);
        acc[j] += __shfl_xor(acc[j], 32);
    }
    __shared__ float red[4][128];
    int w = t >> 6;
    if ((t & 63) < 16) {
#pragma unroll
        for (int j = 0; j < 8; ++j)
            red[w][(t & 15) * 8 + j] = acc[j];
    }
    __syncthreads();
    if (t < 128)
        cn_fin[s * 128 + t] = red[0][t] + red[1][t] + red[2][t] + red[3][t];
}

// ---------------------------------------------------------------------------
// prep: centroids -> chiT/cloT [s][128]; slot 127 = -0.5*|c|^2; grid 256
// ---------------------------------------------------------------------------
__global__ __launch_bounds__(128) void prep_kernel(
    const float* __restrict__ cn_fin,
    unsigned short* __restrict__ chiT, unsigned short* __restrict__ cloT,
    float scale0, int use_qsum)
{
    int s = blockIdx.x, c = threadIdx.x;
    float inv = use_qsum ? 1.f / (cn_fin[s * 128 + 118] + 1e-8f) : scale0;
    float v = (c < 118) ? cn_fin[s * 128 + c] * inv : 0.f;
    float a = v * v;
#pragma unroll
    for (int d = 1; d < 64; d <<= 1) a += __shfl_xor(a, d);
    __shared__ float red[2];
    if ((c & 63) == 0) red[c >> 6] = a;
    __syncthreads();
    float tot = red[0] + red[1];
    unsigned short h, lo;
    if (c == 127) {
        float m2 = -0.5f * tot;
        h = f2bf(m2);
        lo = f2bf(m2 - ubf(h));
    } else {
        h = f2bf(v);
        lo = f2bf(v - ubf(h));
    }
    chiT[s * 128 + c] = h;
    cloT[s * 128 + c] = lo;
}

// ---------------------------------------------------------------------------
// dist: Q[s,n] = softmax_s(2*(cent.pf - 0.5|c|^2)) via MFMA, 3-phase hi/lo
// ---------------------------------------------------------------------------
__global__ __launch_bounds__(256) void dist_kernel(
    const unsigned short* __restrict__ chiT, const unsigned short* __restrict__ cloT,
    const unsigned short* __restrict__ pfTh, const unsigned short* __restrict__ pfTl,
    unsigned short* __restrict__ qh, float* __restrict__ qf, int final_mode)
{
    int t = threadIdx.x;
    int w = t >> 6, l = t & 63;
    int n0 = blockIdx.x * 64 + w * 16;
    int lc = l & 15;
    int lg = l >> 4;

    f32x4 acc[16];
#pragma unroll
    for (int i = 0; i < 16; ++i)
#pragma unroll
        for (int j = 0; j < 4; ++j) acc[i][j] = 0.f;

#pragma unroll
    for (int phse = 0; phse < 3; ++phse) {
        const unsigned short* Ap = (phse == 1) ? cloT : chiT;
        const unsigned short* Bp = (phse == 2) ? pfTl : pfTh;
#pragma unroll
        for (int ks = 0; ks < 4; ++ks) {
            int kb = ks * 32 + 8 * lg;
            bf16x8 bfr = *(const bf16x8*)(Bp + (size_t)(n0 + lc) * 128 + kb);
#pragma unroll
            for (int st = 0; st < 16; ++st) {
                bf16x8 afr = *(const bf16x8*)(Ap + (size_t)(st * 16 + lc) * 128 + kb);
                acc[st] = __builtin_amdgcn_mfma_f32_16x16x32_bf16(afr, bfr, acc[st], 0, 0, 0);
            }
        }
    }

    float m = -1e30f;
#pragma unroll
    for (int st = 0; st < 16; ++st)
#pragma unroll
        for (int r = 0; r < 4; ++r) m = fmaxf(m, acc[st][r]);
    m = fmaxf(m, __shfl_xor(m, 16));
    m = fmaxf(m, __shfl_xor(m, 32));

    float ssum = 0.f;
#pragma unroll
    for (int st = 0; st < 16; ++st)
#pragma unroll
        for (int r = 0; r < 4; ++r) {
            float e = __expf(2.f * (acc[st][r] - m));
            acc[st][r] = e;
            ssum += e;
        }
    ssum += __shfl_xor(ssum, 16);
    ssum += __shfl_xor(ssum, 32);
    float inv = 1.f / ssum;

    int n = n0 + lc;
    if (!final_mode) {
#pragma unroll
        for (int st = 0; st < 16; ++st)
#pragma unroll
            for (int r = 0; r < 4; ++r) {
                int s = st * 16 + lg * 4 + r;
                qh[(size_t)s * HW + n] = f2bf(acc[st][r] * inv);
            }
    } else {
#pragma unroll
        for (int st = 0; st < 16; ++st)
#pragma unroll
            for (int r = 0; r < 4; ++r) {
                int s = st * 16 + lg * 4 + r;
                qf[(size_t)s * HW + n] = acc[st][r] * inv;
            }
    }
}

// ---------------------------------------------------------------------------
// cn: D[s,c] = sum_n Q[s,n]*pf[c,n]
// ---------------------------------------------------------------------------
__global__ __launch_bounds__(512) void cn_kernel(
    const unsigned short* __restrict__ qh, const unsigned short* __restrict__ pfch,
    float* __restrict__ cn_part)
{
    int t = threadIdx.x;
    int w = t >> 6, l = t & 63;
    int lc = l & 15, lg = l >> 4;
    int n0 = blockIdx.x * 512;

    f32x4 acc[16];
#pragma unroll
    for (int i = 0; i < 16; ++i)
#pragma unroll
        for (int j = 0; j < 4; ++j) acc[i][j] = 0.f;

    for (int ks = 0; ks < 16; ++ks) {
        int nb = n0 + ks * 32 + 8 * lg;
        bf16x8 bfr = *(const bf16x8*)(pfch + (size_t)(w * 16 + lc) * HW + nb);
#pragma unroll
        for (int st = 0; st < 16; ++st) {
            bf16x8 afr = *(const bf16x8*)(qh + (size_t)(st * 16 + lc) * HW + nb);
            acc[st] = __builtin_amdgcn_mfma_f32_16x16x32_bf16(afr, bfr, acc[st], 0, 0, 0);
        }
    }

    float* out = cn_part + (size_t)blockIdx.x * 32768;
#pragma unroll
    for (int st = 0; st < 16; ++st)
#pragma unroll
        for (int r = 0; r < 4; ++r) {
            int s = st * 16 + lg * 4 + r;
            out[s * 128 + w * 16 + lc] = acc[st][r];
        }
}

__global__ void reduce_cn(const float* __restrict__ cn_part, float* __restrict__ cn_fin)
{
    int o = blockIdx.x * 256 + threadIdx.x;
    float a = 0.f;
    for (int k = 0; k < 128; ++k) a += cn_part[(size_t)k * 32768 + o];
    cn_fin[o] = a;
}

// ---------------------------------------------------------------------------
extern "C" void kernel_launch(void* const* d_in, const int* in_sizes, int n_in,
                              void* d_out, int out_size, void* d_ws, size_t ws_size,
                              hipStream_t stream)
{
    const float* x     = (const float*)d_in[0];
    const float* s1k7  = (const float*)d_in[1];
    const float* s1k5  = (const float*)d_in[2];
    const float* s1k3  = (const float*)d_in[3];
    const float* s1g   = (const float*)d_in[5];
    const float* s1be  = (const float*)d_in[6];
    const float* s2k7  = (const float*)d_in[7];
    const float* s2k5  = (const float*)d_in[8];
    const float* s2k3  = (const float*)d_in[9];
    const float* s2g   = (const float*)d_in[11];
    const float* s2be  = (const float*)d_in[12];
    const float* s3k7  = (const float*)d_in[13];
    const float* s3k5  = (const float*)d_in[14];
    const float* s3k3  = (const float*)d_in[15];
    const float* s3g   = (const float*)d_in[17];
    const float* s3be  = (const float*)d_in[18];
    const float* outw  = (const float*)d_in[19];
    const float* outb  = (const float*)d_in[20];

    float* ws = (float*)d_ws;
    size_t off = 0;
    unsigned short* wT1h = (unsigned short*)(ws + off); off += 100352;
    unsigned short* wT1l = (unsigned short*)(ws + off); off += 100352;
    unsigned short* wT2h = (unsigned short*)(ws + off); off += 25088;
    unsigned short* wT2l = (unsigned short*)(ws + off); off += 25088;
    unsigned short* wT3h = (unsigned short*)(ws + off); off += 50176;
    unsigned short* wT3l = (unsigned short*)(ws + off); off += 50176;
    float* stats = ws + off; off += 192;
    float* bn    = ws + off; off += 192;
    float* cn_fin= ws + off; off += 32768;
    unsigned short* chiT = (unsigned short*)(ws + off); off += 16384;  // 256*128 bf16 = 16384 floats
    unsigned short* cloT = (unsigned short*)(ws + off); off += 16384;  // (R4 bug: was 8192 -> overlap)
    unsigned short* xTh  = (unsigned short*)(ws + off); off += 4194304;
    unsigned short* xTl  = (unsigned short*)(ws + off); off += 4194304;
    unsigned short* pfch = (unsigned short*)(ws + off); off += 4194304;
    unsigned short* a12H = (unsigned short*)(ws + off); off += 2097152;
    unsigned short* a12L = (unsigned short*)(ws + off); off += 2097152;

    // d_out as scratch: yraw (dead before Q), act3 (dead before Q), cn_part
    char* ob = (char*)d_out;
    float* yraw = (float*)ob;                                    // 8 MB
    unsigned short* qh = (unsigned short*)ob;                    // 32 MB
    float* qf = (float*)ob;                                      // 64 MB final
    float* cn_part = (float*)(ob + (size_t)256 * HW * 2);        // 16 MB @ 32 MB
    unsigned short* a3H = (unsigned short*)(ob + (size_t)256 * HW * 2 + (size_t)128 * 32768 * 4);
    unsigned short* a3L = a3H + (size_t)HW * 32;                 // 8 MB @ 48 MB

    hipMemsetAsync(stats, 0, 192 * sizeof(float), stream);
    wmerge_kernel<<<(49 * 32 * 128 + 255) / 256, 256, 0, stream>>>(s1k7, s1k5, s1k3, 103, 128, wT1h, wT1l);
    wmerge_kernel<<<(49 * 32 * 32 + 255) / 256, 256, 0, stream>>>(s2k7, s2k5, s2k3, 32, 32, wT2h, wT2l);
    wmerge_kernel<<<(49 * 32 * 64 + 255) / 256, 256, 0, stream>>>(s3k7, s3k5, s3k3, 64, 64, wT3h, wT3l);

    transpose_kernel<<<1024, 256, 0, stream>>>(x, xTh, xTl, pfch);

    // stage 1
    convm_kernel<<<512, 256, 0, stream>>>(xTh, xTl, 128, wT1h, wT1l, 128, 4, yraw);
    stats_kernel<<<1024, 256, 0, stream>>>(yraw, stats + 0, stats + 32);
    bnp_kernel<<<1, 32, 0, stream>>>(stats + 0, stats + 32, s1g, s1be, bn + 0, bn + 32);
    bna_kernel<<<1024, 256, 0, stream>>>(yraw, bn + 0, bn + 32, a12H, a12L, 64, 0);

    // stage 2
    convm_kernel<<<512, 256, 0, stream>>>(a12H, a12L, 64, wT2h, wT2l, 32, 1, yraw);
    stats_kernel<<<1024, 256, 0, stream>>>(yraw, stats + 64, stats + 96);
    bnp_kernel<<<1, 32, 0, stream>>>(stats + 64, stats + 96, s2g, s2be, bn + 64, bn + 96);
    bna_kernel<<<1024, 256, 0, stream>>>(yraw, bn + 64, bn + 96, a12H, a12L, 64, 32);

    // stage 3
    convm_kernel<<<512, 256, 0, stream>>>(a12H, a12L, 64, wT3h, wT3l, 64, 2, yraw);
    stats_kernel<<<1024, 256, 0, stream>>>(yraw, stats + 128, stats + 160);
    bnp_kernel<<<1, 32, 0, stream>>>(stats + 128, stats + 160, s3g, s3be, bn + 128, bn + 160);
    bna_kernel<<<1024, 256, 0, stream>>>(yraw, bn + 128, bn + 160, a3H, a3L, 32, 0);

    feat_kernel<<<256, 256, 0, stream>>>(a12H, a12L, a3H, a3L, outw, outb, xTh, xTl, pfch);
    c0_kernel<<<256, 256, 0, stream>>>(xTh, xTl, cn_fin);
    prep_kernel<<<256, 128, 0, stream>>>(cn_fin, chiT, cloT, 1.f / 256.f, 0);

    for (int it = 0; it < 5; ++it) {
        dist_kernel<<<1024, 256, 0, stream>>>(chiT, cloT, xTh, xTl, qh, qf, 0);
        cn_kernel<<<128, 512, 0, stream>>>(qh, pfch, cn_part);
        reduce_cn<<<128, 256, 0, stream>>>(cn_part, cn_fin);
        prep_kernel<<<256, 128, 0, stream>>>(cn_fin, chiT, cloT, 0.f, 1);
    }
    dist_kernel<<<1024, 256, 0, stream>>>(chiT, cloT, xTh, xTl, qh, qf, 1);
}